// Round 2
// baseline (305.122 us; speedup 1.0000x reference)
//
#include <hip/hip_runtime.h>
#include <cstdint>
#include <cstddef>

// ---------------- common helpers ----------------
#define TM 16           // tokens per block
#define IP 136          // padded i-dim (elements, bf16) -> row stride 272 B (17*16B)
#define SLAB (TM * IP)  // 2176 bf16 elements per h-slab

__device__ __forceinline__ unsigned short f2bf(float f) {
  union { float f; unsigned int u; } c; c.f = f;
  unsigned int u = c.u;
  return (unsigned short)((u + 0x7FFFu + ((u >> 16) & 1u)) >> 16);  // RNE
}
__device__ __forceinline__ float bf2f(unsigned short h) {
  union { unsigned int u; float f; } c; c.u = ((unsigned int)h) << 16; return c.f;
}

// unnormalized 32-point Walsh-Hadamard (Sylvester). H32 = WHT/sqrt(32); two
// applications -> /32 folded into coef.
__device__ __forceinline__ void fht32(float* v) {
  #pragma unroll
  for (int s = 1; s < 32; s <<= 1) {
    #pragma unroll
    for (int a = 0; a < 32; ++a) {
      if ((a & s) == 0) {
        float u0 = v[a], u1 = v[a + s];
        v[a] = u0 + u1;
        v[a + s] = u0 - u1;
      }
    }
  }
}

typedef __attribute__((ext_vector_type(8))) short bf16x8;
typedef __attribute__((ext_vector_type(4))) float f32x4;

// ---------------- precompute: scale = mean(|w|) + 1e-8 (double-accurate) ----------------
__global__ void kred1(const float* __restrict__ w, double* __restrict__ partials) {
  const int tid = threadIdx.x;                 // 256 threads
  const int base = blockIdx.x * 1024 + tid;    // 512 blocks * 1024 elems = 524288
  double s = 0.0;
  #pragma unroll
  for (int j = 0; j < 4; ++j) s += (double)fabsf(w[base + j * 256]);
  #pragma unroll
  for (int off = 32; off > 0; off >>= 1) s += __shfl_down(s, off, 64);
  __shared__ double sh[4];
  if ((tid & 63) == 0) sh[tid >> 6] = s;
  __syncthreads();
  if (tid == 0) partials[blockIdx.x] = sh[0] + sh[1] + sh[2] + sh[3];
}

__global__ void kred2(const double* __restrict__ partials,
                      const float* __restrict__ beta,
                      float* __restrict__ scale_out, float* __restrict__ coef) {
  __shared__ double sh[8];
  __shared__ float s_scale;
  const int tid = threadIdx.x;  // 512
  double s = partials[tid];
  #pragma unroll
  for (int off = 32; off > 0; off >>= 1) s += __shfl_down(s, off, 64);
  if ((tid & 63) == 0) sh[tid >> 6] = s;
  __syncthreads();
  if (tid == 0) {
    double t = 0.0;
    #pragma unroll
    for (int k = 0; k < 8; ++k) t += sh[k];
    float sc = (float)(t / 524288.0) + 1e-8f;
    s_scale = sc;
    scale_out[0] = sc;
  }
  __syncthreads();
  const float sc = s_scale;
  // coef[g][o] = beta * scale / 32  (ternary scale factored out of w_q; /32 from 2 FHTs)
  for (int c = tid; c < 4096; c += 512)
    coef[c] = beta[c] * sc * (1.0f / 32.0f);
}

// ---------------- precompute: ternary weights (+-1/0) as bf16 (exact) ----------------
__global__ void kquant(const float* __restrict__ w,
                       const float* __restrict__ scale_p,
                       unsigned short* __restrict__ wq) {
  const float sc = scale_p[0];
  const int base = blockIdx.x * 1024 + threadIdx.x;  // 512 blocks x 256 thr x 4
  #pragma unroll
  for (int j = 0; j < 4; ++j) {
    const int k = base + j * 256;
    float q = rintf(w[k] / sc);                // round-half-to-even, matches np.round
    q = fminf(1.f, fmaxf(-1.f, q));
    wq[k] = f2bf(q);                           // +-1/0 exact in bf16
  }
}

// ---------------- main fused kernel ----------------
// grid 512 blocks (16 tokens each) x 512 threads (8 waves), 136 KB dynamic LDS.
// Phase 1: x*alpha, FHT over g in registers, park xm (bf16) in 32 h-slabs.
// Phase 2: per-h 16x128x128 MFMA GEMM; each slab owned by exactly ONE wave
//          (wave w handles h in {w, w+8, w+16, w+24}) -> in-place yp overwrite race-free.
// Phase 3: FHT over h in registers, * coef, coalesced fp32 store.
__global__ __launch_bounds__(512, 1) void had_main(
    const float* __restrict__ x,
    const unsigned short* __restrict__ wq,
    const float* __restrict__ alpha,
    const float* __restrict__ coef,
    float* __restrict__ y) {
  extern __shared__ unsigned short lds[];  // [32 h][TM t][IP i]
  const int tid = threadIdx.x;
  const long tok0 = (long)blockIdx.x * TM;
  const int i0 = tid & 127;   // column (i or o)
  const int tq = tid >> 7;    // 0..3

  // ---- Phase 1 ----
  {
    float av[32];
    #pragma unroll
    for (int g = 0; g < 32; ++g) av[g] = alpha[g * 128 + i0];
    for (int p = 0; p < 4; ++p) {
      const int t = p * 4 + tq;
      const float* xrow = x + (size_t)(tok0 + t) * 4096 + i0;
      float v[32];
      #pragma unroll
      for (int g = 0; g < 32; ++g) v[g] = xrow[(size_t)g * 128] * av[g];
      fht32(v);
      #pragma unroll
      for (int h = 0; h < 32; ++h) lds[(h * TM + t) * IP + i0] = f2bf(v[h]);
    }
  }
  __syncthreads();

  // ---- Phase 2 ----
  {
    const int wave = tid >> 6;
    const int lane = tid & 63;
    const int m = lane & 15;       // A-row (t) / B-col (o) / C-col (o)
    const int quad = lane >> 4;    // k-chunk; C-row group
    for (int hh = 0; hh < 4; ++hh) {
      const int h = wave + hh * 8;
      unsigned short* slab = lds + h * SLAB;
      bf16x8 afr[4];
      #pragma unroll
      for (int ks = 0; ks < 4; ++ks)   // A[m=t][k = ks*32 + quad*8 + j]
        afr[ks] = *(const bf16x8*)(slab + m * IP + ks * 32 + quad * 8);
      const unsigned short* wh = wq + h * 16384 + quad * 8;
      #pragma unroll
      for (int nt = 0; nt < 8; ++nt) {
        f32x4 acc = {0.f, 0.f, 0.f, 0.f};
        const unsigned short* wb = wh + (nt * 16 + m) * 128;  // B[k][n]=wq[h][n][k]
        #pragma unroll
        for (int ks = 0; ks < 4; ++ks) {
          bf16x8 bfr = *(const bf16x8*)(wb + ks * 32);
          acc = __builtin_amdgcn_mfma_f32_16x16x32_bf16(afr[ks], bfr, acc, 0, 0, 0);
        }
        // C layout: col = lane&15 (o), row = quad*4 + r (t). Park yp (bf16) in slab h.
        #pragma unroll
        for (int r = 0; r < 4; ++r)
          slab[(quad * 4 + r) * IP + nt * 16 + m] = f2bf(acc[r]);
      }
    }
  }
  __syncthreads();

  // ---- Phase 3 ----
  {
    float cf[32];
    #pragma unroll
    for (int g = 0; g < 32; ++g) cf[g] = coef[g * 128 + i0];
    for (int p = 0; p < 4; ++p) {
      const int t = p * 4 + tq;
      float v[32];
      #pragma unroll
      for (int h = 0; h < 32; ++h) v[h] = bf2f(lds[(h * TM + t) * IP + i0]);
      fht32(v);
      float* yrow = y + (size_t)(tok0 + t) * 4096 + i0;
      #pragma unroll
      for (int g = 0; g < 32; ++g) yrow[(size_t)g * 128] = v[g] * cf[g];
    }
  }
}

// ---------------- launcher ----------------
extern "C" void kernel_launch(void* const* d_in, const int* in_sizes, int n_in,
                              void* d_out, int out_size, void* d_ws, size_t ws_size,
                              hipStream_t stream) {
  (void)in_sizes; (void)n_in; (void)out_size; (void)ws_size;
  const float* x     = (const float*)d_in[0];  // fp32 [4,2048,4096]
  const float* w     = (const float*)d_in[1];  // fp32 [32,128,128]
  const float* alpha = (const float*)d_in[2];  // fp32 [32,128]
  const float* beta  = (const float*)d_in[3];  // fp32 [32,128]
  float* y = (float*)d_out;                    // fp32 out

  char* ws = (char*)d_ws;
  unsigned short* wq = (unsigned short*)(ws);        // 1 MB ternary bf16
  float* coef      = (float*)(ws + 1048576);         // 16 KB
  float* scale     = (float*)(ws + 1064960);         // 4 B
  double* partials = (double*)(ws + 1065472);        // 512 doubles

  (void)hipFuncSetAttribute(reinterpret_cast<const void*>(had_main),
                            hipFuncAttributeMaxDynamicSharedMemorySize, 139264);

  hipLaunchKernelGGL(kred1,    dim3(512), dim3(256), 0,      stream, w, partials);
  hipLaunchKernelGGL(kred2,    dim3(1),   dim3(512), 0,      stream, partials, beta, scale, coef);
  hipLaunchKernelGGL(kquant,   dim3(512), dim3(256), 0,      stream, w, scale, wq);
  hipLaunchKernelGGL(had_main, dim3(512), dim3(512), 139264, stream, x, wq, alpha, coef, y);
}

// Round 3
// 279.298 us; speedup vs baseline: 1.0925x; 1.0925x over previous
//
#include <hip/hip_runtime.h>
#include <cstdint>
#include <cstddef>

// ---------------- common ----------------
#define TM 8            // tokens per block
#define IP 136          // padded i-dim (bf16 elems) -> row stride 272 B (17*16B, b128-aligned)
#define SLAB (TM * IP)  // 1088 bf16 per h-slab; 32 slabs = 69632 B LDS -> 2 blocks/CU

__device__ __forceinline__ unsigned short f2bf(float f) {
  union { float f; unsigned int u; } c; c.f = f;
  unsigned int u = c.u;
  return (unsigned short)((u + 0x7FFFu + ((u >> 16) & 1u)) >> 16);  // RNE
}
__device__ __forceinline__ float bf2f(unsigned short h) {
  union { unsigned int u; float f; } c; c.u = ((unsigned int)h) << 16; return c.f;
}

// unnormalized 32-pt Walsh-Hadamard; two applications -> /32 folded into beta*scale/32
__device__ __forceinline__ void fht32(float* v) {
  #pragma unroll
  for (int s = 1; s < 32; s <<= 1) {
    #pragma unroll
    for (int a = 0; a < 32; ++a) {
      if ((a & s) == 0) {
        float u0 = v[a], u1 = v[a + s];
        v[a] = u0 + u1;
        v[a + s] = u0 - u1;
      }
    }
  }
}

typedef __attribute__((ext_vector_type(8))) short bf16x8;
typedef __attribute__((ext_vector_type(4))) float f32x4;

// ---------------- pre-pass 1: partial sums of |w| ----------------
__global__ void kred1(const float* __restrict__ w, double* __restrict__ partials) {
  const int tid = threadIdx.x;                   // 256 thr, 64 blocks
  const int base = blockIdx.x * 8192 + tid;
  double s = 0.0;
  #pragma unroll
  for (int j = 0; j < 32; ++j) s += (double)fabsf(w[base + j * 256]);
  #pragma unroll
  for (int off = 32; off > 0; off >>= 1) s += __shfl_down(s, off, 64);
  __shared__ double sh[4];
  if ((tid & 63) == 0) sh[tid >> 6] = s;
  __syncthreads();
  if (tid == 0) partials[blockIdx.x] = sh[0] + sh[1] + sh[2] + sh[3];
}

// ---------------- pre-pass 2: scale + ternary quantize into fragment-order layout ----
// wqt chunk c (c = blockIdx*256+tid, 65536 chunks of 8 bf16): decode
//   lane=c&63, ks=(c>>6)&3, nt=(c>>8)&7, h=c>>11, m=lane&15, quad=lane>>4
//   holds wq[h][nt*16+m][ks*32+quad*8 .. +8]  -> phase-2 wave loads are 1KB contiguous.
__global__ void kprep(const float* __restrict__ w, const double* __restrict__ partials,
                      float* __restrict__ scale_out, unsigned short* __restrict__ wqt) {
  const int tid = threadIdx.x;  // 256 thr, 256 blocks
  __shared__ float s_sc;
  if (tid < 64) {                       // deterministic redundant re-reduce (4 KB)
    double s = partials[tid];
    #pragma unroll
    for (int off = 32; off > 0; off >>= 1) s += __shfl_down(s, off, 64);
    if (tid == 0) s_sc = (float)(s / 524288.0) + 1e-8f;
  }
  __syncthreads();
  const float sc = s_sc;
  if (blockIdx.x == 0 && tid == 0) scale_out[0] = sc;
  const int cid = blockIdx.x * 256 + tid;
  const int lane = cid & 63, ks = (cid >> 6) & 3, nt = (cid >> 8) & 7, h = cid >> 11;
  const int m = lane & 15, quad = lane >> 4;
  const float* src = w + h * 16384 + (nt * 16 + m) * 128 + ks * 32 + quad * 8;
  bf16x8 vv;
  #pragma unroll
  for (int j = 0; j < 8; ++j) {
    float q = rintf(src[j] / sc);              // round-half-even == np.round
    q = fminf(1.f, fmaxf(-1.f, q));
    vv[j] = (short)f2bf(q);                    // +-1/0 exact in bf16
  }
  *(bf16x8*)(wqt + (size_t)cid * 8) = vv;
}

// ---------------- main fused kernel ----------------
// grid 1024 blocks (8 tokens) x 512 thr (8 waves), 69632 B dynamic LDS -> 2 blocks/CU.
// P1: x*alpha, FHT over g in regs, park xm (bf16) in 32 h-slabs.
// P2: per-h MFMA (M=8 of 16 rows used); wave w owns h in {w,w+8,w+16,w+24} ->
//     each slab touched by ONE wave, in-place yp overwrite race-free, no barriers.
// P3: FHT over h in regs, * beta*scale/32, coalesced fp32 store.
__global__ __launch_bounds__(512, 4) void had_main(
    const float* __restrict__ x,
    const unsigned short* __restrict__ wqt,
    const float* __restrict__ alpha,
    const float* __restrict__ beta,
    const float* __restrict__ scale_p,
    float* __restrict__ y) {
  extern __shared__ unsigned short lds[];  // [32 h][TM t][IP i]
  const int tid = threadIdx.x;
  const long tok0 = (long)blockIdx.x * TM;
  const int i0 = tid & 127;
  const int tq = tid >> 7;    // 0..3

  // ---- Phase 1 ----
  {
    float av[32];
    #pragma unroll
    for (int g = 0; g < 32; ++g) av[g] = alpha[g * 128 + i0];
    #pragma unroll
    for (int p = 0; p < 2; ++p) {
      const int t = p * 4 + tq;
      const float* xrow = x + (size_t)(tok0 + t) * 4096 + i0;
      float v[32];
      #pragma unroll
      for (int g = 0; g < 32; ++g) v[g] = xrow[(size_t)g * 128] * av[g];
      fht32(v);
      #pragma unroll
      for (int h = 0; h < 32; ++h) lds[(h * TM + t) * IP + i0] = f2bf(v[h]);
    }
  }
  __syncthreads();

  // ---- Phase 2 ----
  {
    const int wave = tid >> 6;
    const int lane = tid & 63;
    const int m = lane & 15;       // B-col (o) / C-col (o); A-row (t) mod 8
    const int quad = lane >> 4;    // k-chunk; C-row group
    for (int hh = 0; hh < 4; ++hh) {
      const int h = wave + hh * 8;
      unsigned short* slab = lds + h * SLAB;
      bf16x8 afr[4];
      #pragma unroll
      for (int ks = 0; ks < 4; ++ks)   // A[t = m&7][k = ks*32 + quad*8 + j]
        afr[ks] = *(const bf16x8*)(slab + (m & 7) * IP + ks * 32 + quad * 8);
      const unsigned short* wh = wqt + ((size_t)h * 8) * 2048;  // h-major chunks
      #pragma unroll
      for (int nt = 0; nt < 8; ++nt) {
        f32x4 acc = {0.f, 0.f, 0.f, 0.f};
        #pragma unroll
        for (int ks = 0; ks < 4; ++ks) {
          // contiguous: ((h*8+nt)*4+ks)*512 + lane*8  -> 1KB/wave b128 stream
          bf16x8 bfr = *(const bf16x8*)(wh + (size_t)(nt * 4 + ks) * 512 + lane * 8);
          acc = __builtin_amdgcn_mfma_f32_16x16x32_bf16(afr[ks], bfr, acc, 0, 0, 0);
        }
        // C: col = m (o), row = quad*4+r (t). Rows 8..15 duplicate 0..7 -> skip.
        if (quad < 2) {
          #pragma unroll
          for (int r = 0; r < 4; ++r)
            slab[(quad * 4 + r) * IP + nt * 16 + m] = f2bf(acc[r]);
        }
      }
    }
  }
  __syncthreads();

  // ---- Phase 3 ----
  {
    const float sc32 = scale_p[0] * (1.0f / 32.0f);
    float cf[32];
    #pragma unroll
    for (int g = 0; g < 32; ++g) cf[g] = beta[g * 128 + i0] * sc32;
    #pragma unroll
    for (int p = 0; p < 2; ++p) {
      const int t = p * 4 + tq;
      float v[32];
      #pragma unroll
      for (int h = 0; h < 32; ++h) v[h] = bf2f(lds[(h * TM + t) * IP + i0]);
      fht32(v);
      float* yrow = y + (size_t)(tok0 + t) * 4096 + i0;
      #pragma unroll
      for (int g = 0; g < 32; ++g) yrow[(size_t)g * 128] = v[g] * cf[g];
    }
  }
}

// ---------------- launcher ----------------
extern "C" void kernel_launch(void* const* d_in, const int* in_sizes, int n_in,
                              void* d_out, int out_size, void* d_ws, size_t ws_size,
                              hipStream_t stream) {
  (void)in_sizes; (void)n_in; (void)out_size; (void)ws_size;
  const float* x     = (const float*)d_in[0];  // fp32 [4,2048,4096]
  const float* w     = (const float*)d_in[1];  // fp32 [32,128,128]
  const float* alpha = (const float*)d_in[2];  // fp32 [32,128]
  const float* beta  = (const float*)d_in[3];  // fp32 [32,128]
  float* y = (float*)d_out;

  char* ws = (char*)d_ws;
  unsigned short* wqt = (unsigned short*)(ws);   // 1 MB ternary bf16, fragment order
  float* scale     = (float*)(ws + 1048576);     // 4 B
  double* partials = (double*)(ws + 1048584);    // 64 doubles (8-aligned)

  (void)hipFuncSetAttribute(reinterpret_cast<const void*>(had_main),
                            hipFuncAttributeMaxDynamicSharedMemorySize, 69632);

  hipLaunchKernelGGL(kred1,    dim3(64),   dim3(256), 0,     stream, w, partials);
  hipLaunchKernelGGL(kprep,    dim3(256),  dim3(256), 0,     stream, w, partials, scale, wqt);
  hipLaunchKernelGGL(had_main, dim3(1024), dim3(512), 69632, stream, x, wqt, alpha, beta, scale, y);
}

// Round 4
// 273.428 us; speedup vs baseline: 1.1159x; 1.0215x over previous
//
#include <hip/hip_runtime.h>
#include <cstdint>
#include <cstddef>

// ---------------- common ----------------
#define TM 8            // tokens per block
#define IP 136          // padded i-dim (bf16 elems) -> row stride 272 B (17*16B, b128-aligned)
#define SLAB (TM * IP)  // 1088 bf16 per h-slab; 32 slabs = 69632 B LDS -> 2 blocks/CU

__device__ __forceinline__ unsigned short f2bf(float f) {
  union { float f; unsigned int u; } c; c.f = f;
  unsigned int u = c.u;
  return (unsigned short)((u + 0x7FFFu + ((u >> 16) & 1u)) >> 16);  // RNE
}
__device__ __forceinline__ float bf2f(unsigned short h) {
  union { unsigned int u; float f; } c; c.u = ((unsigned int)h) << 16; return c.f;
}

// unnormalized 32-pt Walsh-Hadamard; two applications -> /32 folded into beta*scale/32
__device__ __forceinline__ void fht32(float* v) {
  #pragma unroll
  for (int s = 1; s < 32; s <<= 1) {
    #pragma unroll
    for (int a = 0; a < 32; ++a) {
      if ((a & s) == 0) {
        float u0 = v[a], u1 = v[a + s];
        v[a] = u0 + u1;
        v[a + s] = u0 - u1;
      }
    }
  }
}

typedef __attribute__((ext_vector_type(8))) short bf16x8;
typedef __attribute__((ext_vector_type(4))) float f32x4;

// ---------------- pre-pass 1: partial sums of |w| (256 blocks) ----------------
__global__ void kred1(const float* __restrict__ w, double* __restrict__ partials) {
  const int tid = threadIdx.x;                   // 256 thr, 256 blocks
  const int base = blockIdx.x * 2048 + tid;
  double s = 0.0;
  #pragma unroll
  for (int j = 0; j < 8; ++j) s += (double)fabsf(w[base + j * 256]);
  #pragma unroll
  for (int off = 32; off > 0; off >>= 1) s += __shfl_down(s, off, 64);
  __shared__ double sh[4];
  if ((tid & 63) == 0) sh[tid >> 6] = s;
  __syncthreads();
  if (tid == 0) partials[blockIdx.x] = sh[0] + sh[1] + sh[2] + sh[3];
}

// ---------------- pre-pass 2: scale + ternary quantize into fragment order ------
// wqt chunk c (c = blockIdx*256+tid, 65536 chunks of 8 bf16):
//   lane=c&63, ks=(c>>6)&3, nt=(c>>8)&7, h=c>>11, m=lane&15, quad=lane>>4
//   holds wq[h][nt*16+m][ks*32+quad*8 .. +8]  -> phase-2 wave loads fully coalesced.
__global__ void kprep(const float* __restrict__ w, const double* __restrict__ partials,
                      float* __restrict__ scale_out, unsigned short* __restrict__ wqt) {
  const int tid = threadIdx.x;  // 256 thr, 256 blocks
  __shared__ float s_sc;
  if (tid < 64) {               // deterministic redundant re-reduce of 256 partials
    double s = partials[tid] + partials[tid + 64] + partials[tid + 128] + partials[tid + 192];
    #pragma unroll
    for (int off = 32; off > 0; off >>= 1) s += __shfl_down(s, off, 64);
    if (tid == 0) s_sc = (float)(s / 524288.0) + 1e-8f;
  }
  __syncthreads();
  const float sc = s_sc;
  if (blockIdx.x == 0 && tid == 0) scale_out[0] = sc;
  const int cid = blockIdx.x * 256 + tid;
  const int lane = cid & 63, ks = (cid >> 6) & 3, nt = (cid >> 8) & 7, h = cid >> 11;
  const int m = lane & 15, quad = lane >> 4;
  const float* src = w + h * 16384 + (nt * 16 + m) * 128 + ks * 32 + quad * 8;
  bf16x8 vv;
  #pragma unroll
  for (int j = 0; j < 8; ++j) {
    float q = rintf(src[j] / sc);              // round-half-even == np.round
    q = fminf(1.f, fmaxf(-1.f, q));
    vv[j] = (short)f2bf(q);                    // +-1/0 exact in bf16
  }
  *(bf16x8*)(wqt + (size_t)cid * 8) = vv;
}

// ---------------- main fused kernel ----------------
// grid 1024 blocks (8 tokens) x 512 thr (8 waves), 69632 B dynamic LDS -> 2 blocks/CU.
// P1: batched x loads (2 tokens to regs), *alpha, FHT over g, park xm (bf16) slabs.
// P2: per-h MFMA with 1-deep B-fragment prefetch; wave w owns h in {w,w+8,w+16,w+24}
//     -> each slab touched by ONE wave, in-place yp overwrite race-free.
// P3: FHT over h in regs, * beta*scale/32, coalesced fp32 store.
__global__ __launch_bounds__(512, 4) void had_main(
    const float* __restrict__ x,
    const unsigned short* __restrict__ wqt,
    const float* __restrict__ alpha,
    const float* __restrict__ beta,
    const float* __restrict__ scale_p,
    float* __restrict__ y) {
  extern __shared__ unsigned short lds[];  // [32 h][TM t][IP i]
  const int tid = threadIdx.x;
  const long tok0 = (long)blockIdx.x * TM;
  const int i0 = tid & 127;
  const int tq = tid >> 7;    // 0..3; covers t = tq and tq+4

  // ---- Phase 1 ----
  {
    const float* xrowA = x + (size_t)(tok0 + tq) * 4096 + i0;
    const float* xrowB = x + (size_t)(tok0 + tq + 4) * 4096 + i0;
    float va[32], vb[32];
    #pragma unroll
    for (int g = 0; g < 32; ++g) va[g] = xrowA[(size_t)g * 128];  // 64 loads batched
    #pragma unroll
    for (int g = 0; g < 32; ++g) vb[g] = xrowB[(size_t)g * 128];
    #pragma unroll
    for (int g = 0; g < 32; ++g) {
      const float a = alpha[g * 128 + i0];
      va[g] *= a; vb[g] *= a;
    }
    fht32(va);
    #pragma unroll
    for (int h = 0; h < 32; ++h) lds[(h * TM + tq) * IP + i0] = f2bf(va[h]);
    fht32(vb);
    #pragma unroll
    for (int h = 0; h < 32; ++h) lds[(h * TM + tq + 4) * IP + i0] = f2bf(vb[h]);
  }
  __syncthreads();

  // ---- Phase 2 ----
  {
    const int wave = tid >> 6;
    const int lane = tid & 63;
    const int m = lane & 15;       // B-col (o) / C-col (o); A-row (t) = m&7
    const int quad = lane >> 4;    // k-chunk; C-row group
    #pragma unroll
    for (int hh = 0; hh < 4; ++hh) {
      const int h = wave + hh * 8;
      unsigned short* slab = lds + h * SLAB;
      bf16x8 afr[4];
      #pragma unroll
      for (int ks = 0; ks < 4; ++ks)   // A[t=m&7][k = ks*32 + quad*8 + j]
        afr[ks] = *(const bf16x8*)(slab + (m & 7) * IP + ks * 32 + quad * 8);
      const unsigned short* wh = wqt + (size_t)h * 16384 + (size_t)lane * 8;
      bf16x8 cur[4], nxt[4];
      #pragma unroll
      for (int ks = 0; ks < 4; ++ks) cur[ks] = *(const bf16x8*)(wh + ks * 512);
      #pragma unroll
      for (int nt = 0; nt < 8; ++nt) {
        if (nt < 7) {
          #pragma unroll
          for (int ks = 0; ks < 4; ++ks)   // prefetch next nt during this MFMA chain
            nxt[ks] = *(const bf16x8*)(wh + (size_t)((nt + 1) * 4 + ks) * 512);
        }
        f32x4 acc = {0.f, 0.f, 0.f, 0.f};
        #pragma unroll
        for (int ks = 0; ks < 4; ++ks)
          acc = __builtin_amdgcn_mfma_f32_16x16x32_bf16(afr[ks], cur[ks], acc, 0, 0, 0);
        // C: col = m (o), row = quad*4+r (t). Rows 8..15 duplicate 0..7 -> skip.
        if (quad < 2) {
          #pragma unroll
          for (int r = 0; r < 4; ++r)
            slab[(quad * 4 + r) * IP + nt * 16 + m] = f2bf(acc[r]);
        }
        #pragma unroll
        for (int ks = 0; ks < 4; ++ks) cur[ks] = nxt[ks];
      }
    }
  }
  __syncthreads();

  // ---- Phase 3 ----
  {
    const float sc32 = scale_p[0] * (1.0f / 32.0f);
    float cf[32];
    #pragma unroll
    for (int g = 0; g < 32; ++g) cf[g] = beta[g * 128 + i0] * sc32;
    #pragma unroll
    for (int p = 0; p < 2; ++p) {
      const int t = tq + p * 4;
      float v[32];
      #pragma unroll
      for (int h = 0; h < 32; ++h) v[h] = bf2f(lds[(h * TM + t) * IP + i0]);
      fht32(v);
      float* yrow = y + (size_t)(tok0 + t) * 4096 + i0;
      #pragma unroll
      for (int g = 0; g < 32; ++g) yrow[(size_t)g * 128] = v[g] * cf[g];
    }
  }
}

// ---------------- launcher ----------------
extern "C" void kernel_launch(void* const* d_in, const int* in_sizes, int n_in,
                              void* d_out, int out_size, void* d_ws, size_t ws_size,
                              hipStream_t stream) {
  (void)in_sizes; (void)n_in; (void)out_size; (void)ws_size;
  const float* x     = (const float*)d_in[0];  // fp32 [4,2048,4096]
  const float* w     = (const float*)d_in[1];  // fp32 [32,128,128]
  const float* alpha = (const float*)d_in[2];  // fp32 [32,128]
  const float* beta  = (const float*)d_in[3];  // fp32 [32,128]
  float* y = (float*)d_out;

  char* ws = (char*)d_ws;
  unsigned short* wqt = (unsigned short*)(ws);   // 1 MB ternary bf16, fragment order
  float* scale     = (float*)(ws + 1048576);     // 4 B
  double* partials = (double*)(ws + 1048584);    // 256 doubles (8-aligned)

  (void)hipFuncSetAttribute(reinterpret_cast<const void*>(had_main),
                            hipFuncAttributeMaxDynamicSharedMemorySize, 69632);

  hipLaunchKernelGGL(kred1,    dim3(256),  dim3(256), 0,     stream, w, partials);
  hipLaunchKernelGGL(kprep,    dim3(256),  dim3(256), 0,     stream, w, partials, scale, wqt);
  hipLaunchKernelGGL(had_main, dim3(1024), dim3(512), 69632, stream, x, wqt, alpha, beta, scale, y);
}